// Round 9
// baseline (402.555 us; speedup 1.0000x reference)
//
#include <hip/hip_runtime.h>
#include <math.h>

// ---------------------------------------------------------------------------
// GCN link predictor on MI355X, round 9.
// R8 post-mortem: top-5 is now the harness ws-poison fill (uncontrollable).
// R9: apply the round-7 MLP lesson to the head (LDS B-frags free 64 VGPR;
// 2-chunk processing -> 8 z-row gathers in flight/wave), NT-protect the CSR
// stream in the agg kernels (L2 residency for the xw gather set), fuse the
// 3 weight-prep launches into 1.
// ---------------------------------------------------------------------------

typedef __attribute__((ext_vector_type(8))) short short8x;
typedef __attribute__((ext_vector_type(4))) float f32x4;

__device__ __forceinline__ unsigned short f2bf(float f) {
  unsigned int u = __float_as_uint(f);
  unsigned int r = u + 0x7FFFu + ((u >> 16) & 1u);  // RNE
  return (unsigned short)(r >> 16);
}
__device__ __forceinline__ float bf2f(unsigned short u) {
  return __uint_as_float(((unsigned int)u) << 16);
}

// ------------------------------ graph build --------------------------------

__global__ void zero_int_kernel(int* __restrict__ p, int n) {
  int i = blockIdx.x * blockDim.x + threadIdx.x;
  if (i < n) p[i] = 0;
}

// Per-block LDS histogram over buckets (col>>8); one global atomic per
// (block,bucket). 4096 edges/block.
__global__ __launch_bounds__(256) void binA_hist_kernel(const int* __restrict__ col,
                                                        int* __restrict__ bucket_count, int E,
                                                        int NBK) {
  __shared__ int hist[256];
  const int tid = threadIdx.x;
  hist[tid] = 0;
  __syncthreads();
  const int base = blockIdx.x * 4096;
#pragma unroll
  for (int j = 0; j < 16; ++j) {
    int i = base + j * 256 + tid;
    if (i < E) atomicAdd(&hist[((unsigned int)__builtin_nontemporal_load(&col[i])) >> 8], 1);
  }
  __syncthreads();
  if (tid < NBK) {
    int h = hist[tid];
    if (h) atomicAdd(&bucket_count[tid], h);
  }
}

// Single block: exclusive scan of NBK (<=256) bucket counts.
__global__ __launch_bounds__(256) void scan_buckets_kernel(const int* __restrict__ bucket_count,
                                                           int* __restrict__ bucket_start,
                                                           int* __restrict__ bcur,
                                                           int* __restrict__ offs_n, int NBK,
                                                           int E) {
  __shared__ int ws[4];
  const int tid = threadIdx.x;
  const int lane = tid & 63;
  const int wid = tid >> 6;
  int v = (tid < NBK) ? bucket_count[tid] : 0;
  int incl = v;
#pragma unroll
  for (int d = 1; d < 64; d <<= 1) {
    int t = __shfl_up(incl, d, 64);
    if (lane >= d) incl += t;
  }
  if (lane == 63) ws[wid] = incl;
  __syncthreads();
  int woff = 0;
#pragma unroll
  for (int w = 0; w < 4; ++w)
    if (w < wid) woff += ws[w];
  int excl = woff + incl - v;
  if (tid < NBK) {
    bucket_start[tid] = excl;
    bcur[tid] = excl;
  }
  if (tid == 0) {
    bucket_start[NBK] = E;
    *offs_n = E;
  }
}

// binA_scatter: 4096 edges/block; LDS hist -> one global atomicAdd per
// (block,bucket) reserve -> LDS-cursor scatter of packed (col<<16|row).
__global__ __launch_bounds__(256) void binA_scatter_kernel(const int* __restrict__ row,
                                                           const int* __restrict__ col,
                                                           int* __restrict__ bcur,
                                                           unsigned int* __restrict__ staging,
                                                           int E, int NBK) {
  __shared__ int hist[256];
  const int tid = threadIdx.x;
  hist[tid] = 0;
  __syncthreads();
  const int base = blockIdx.x * 4096;
  unsigned int payload[16];
  int bk[16];
#pragma unroll
  for (int j = 0; j < 16; ++j) {
    int i = base + j * 256 + tid;
    if (i < E) {
      unsigned int c = (unsigned int)__builtin_nontemporal_load(&col[i]);
      unsigned int r = (unsigned int)__builtin_nontemporal_load(&row[i]);
      payload[j] = (c << 16) | r;
      bk[j] = (int)(c >> 8);
      atomicAdd(&hist[bk[j]], 1);
    } else {
      bk[j] = -1;
    }
  }
  __syncthreads();
  if (tid < NBK) {
    int h = hist[tid];
    hist[tid] = h ? atomicAdd(&bcur[tid], h) : 0;
  }
  __syncthreads();
#pragma unroll
  for (int j = 0; j < 16; ++j) {
    if (bk[j] >= 0) {
      int p = atomicAdd(&hist[bk[j]], 1);
      staging[p] = payload[j];
    }
  }
}

// binB1: one block per 256-node bucket. LDS node-histogram of the bucket's
// staging segment -> LDS scan -> writes offs[node] and dinv[node].
__global__ __launch_bounds__(256) void binB1_kernel(const unsigned int* __restrict__ staging,
                                                    const int* __restrict__ bucket_start,
                                                    int* __restrict__ offs,
                                                    float* __restrict__ dinv, int N) {
  __shared__ int cnt[256];
  __shared__ int ws[4];
  const int b = blockIdx.x;
  const int n0 = b * 256;
  const int tid = threadIdx.x;
  cnt[tid] = 0;
  __syncthreads();
  const int s = bucket_start[b];
  const int e = bucket_start[b + 1];
  for (int t = s + tid; t < e; t += 256) {
    atomicAdd(&cnt[(staging[t] >> 16) & 255u], 1);
  }
  __syncthreads();
  const int deg = cnt[tid];
  const int lane = tid & 63;
  const int wid = tid >> 6;
  int incl = deg;
#pragma unroll
  for (int d = 1; d < 64; d <<= 1) {
    int t = __shfl_up(incl, d, 64);
    if (lane >= d) incl += t;
  }
  if (lane == 63) ws[wid] = incl;
  __syncthreads();
  int woff = 0;
#pragma unroll
  for (int w = 0; w < 4; ++w)
    if (w < wid) woff += ws[w];
  const int excl = woff + incl - deg;
  const int node = n0 + tid;
  if (node < N) {
    offs[node] = s + excl;
    dinv[node] = rsqrtf((float)deg + 1.0f);
  }
}

// binB2: fine scatter into CSR with packed bf16 dinv.
__global__ __launch_bounds__(512) void binB2_kernel(const unsigned int* __restrict__ staging,
                                                    const int* __restrict__ offs,
                                                    const int* __restrict__ bucket_start,
                                                    const float* __restrict__ dinv,
                                                    unsigned int* __restrict__ csr, int N) {
  __shared__ int cur[256];
  const int b = blockIdx.x;
  const int n0 = b * 256;
  const int tid = threadIdx.x;
  if (tid < 256 && n0 + tid < N) cur[tid] = offs[n0 + tid];
  __syncthreads();
  const int s = bucket_start[b];
  const int e = bucket_start[b + 1];
  for (int t = s + tid; t < e; t += 512) {
    unsigned int v = __builtin_nontemporal_load(&staging[t]);
    int cl = (int)((v >> 16) & 255u);
    unsigned int r = v & 0xFFFFu;
    unsigned int wd = f2bf(dinv[r]);
    int p = atomicAdd(&cur[cl], 1);
    csr[p] = (wd << 16) | r;
  }
}

// --------------------- weight prep (fused, one launch) ---------------------
__device__ __forceinline__ void prep_one(const float* __restrict__ W,
                                         unsigned short* __restrict__ out, int K, int N, int idx) {
  int KS = K / 32;
  int lane = idx & 63;
  int t = idx >> 6;
  int ks = t % KS;
  int nt = t / KS;
  int n = nt * 16 + (lane & 15);
  int k0 = ks * 32 + (lane >> 4) * 8;
  unsigned short* o = out + (size_t)idx * 8;
#pragma unroll
  for (int j = 0; j < 8; ++j) o[j] = f2bf(W[(size_t)(k0 + j) * N + n]);
}

__global__ __launch_bounds__(256) void prep_all_kernel(
    const float* __restrict__ W1, const float* __restrict__ W2, const float* __restrict__ H,
    unsigned short* __restrict__ bfW1, unsigned short* __restrict__ bfW2,
    unsigned short* __restrict__ bfH) {
  int idx = blockIdx.x * 256 + threadIdx.x;
  if (idx < 8192) {
    prep_one(W1, bfW1, 512, 128, idx);
  } else if (idx < 9216) {
    prep_one(W2, bfW2, 128, 64, idx - 8192);
  } else if (idx < 10240) {
    prep_one(H, bfH, 128, 64, idx - 9216);
  }
}

// ------------------------------- MFMA GEMM ---------------------------------
template <int K, int N, bool ABF16>
__global__ __launch_bounds__(256) void mfma_gemm_kernel(const void* __restrict__ Ap,
                                                        const unsigned short* __restrict__ Bfrag,
                                                        unsigned short* __restrict__ Cout, int M) {
  constexpr int KS = K / 32;
  constexpr int NT = N / 16;
  const int lane = threadIdx.x & 63;
  const int wid = threadIdx.x >> 6;
  const int quad = lane >> 4;
  const int lc = lane & 15;
  const int mbase = blockIdx.x * 128 + wid * 32;
  if (mbase >= M) return;

  f32x4 acc[2][NT];
#pragma unroll
  for (int mt = 0; mt < 2; ++mt)
#pragma unroll
    for (int nt = 0; nt < NT; ++nt) acc[mt][nt] = (f32x4){0.f, 0.f, 0.f, 0.f};

  int r0 = mbase + lc;
  int r1 = mbase + 16 + lc;
  if (r0 >= M) r0 = M - 1;
  if (r1 >= M) r1 = M - 1;

#pragma unroll
  for (int ks = 0; ks < KS; ++ks) {
    const int k0 = ks * 32 + quad * 8;
    short8x a[2];
    if constexpr (ABF16) {
      const unsigned short* A = (const unsigned short*)Ap;
      a[0] = *(const short8x*)(A + (size_t)r0 * K + k0);
      a[1] = *(const short8x*)(A + (size_t)r1 * K + k0);
    } else {
      const float* A = (const float*)Ap;
      const float4* p0 = (const float4*)(A + (size_t)r0 * K + k0);
      const float4* p1 = (const float4*)(A + (size_t)r1 * K + k0);
      float4 u0 = p0[0], v0 = p0[1];
      float4 u1 = p1[0], v1 = p1[1];
      short8x t0, t1;
      t0[0] = (short)f2bf(u0.x); t0[1] = (short)f2bf(u0.y);
      t0[2] = (short)f2bf(u0.z); t0[3] = (short)f2bf(u0.w);
      t0[4] = (short)f2bf(v0.x); t0[5] = (short)f2bf(v0.y);
      t0[6] = (short)f2bf(v0.z); t0[7] = (short)f2bf(v0.w);
      t1[0] = (short)f2bf(u1.x); t1[1] = (short)f2bf(u1.y);
      t1[2] = (short)f2bf(u1.z); t1[3] = (short)f2bf(u1.w);
      t1[4] = (short)f2bf(v1.x); t1[5] = (short)f2bf(v1.y);
      t1[6] = (short)f2bf(v1.z); t1[7] = (short)f2bf(v1.w);
      a[0] = t0;
      a[1] = t1;
    }
#pragma unroll
    for (int nt = 0; nt < NT; ++nt) {
      short8x b = *(const short8x*)(Bfrag + (((size_t)nt * KS + ks) * 64 + lane) * 8);
      acc[0][nt] = __builtin_amdgcn_mfma_f32_16x16x32_bf16(a[0], b, acc[0][nt], 0, 0, 0);
      acc[1][nt] = __builtin_amdgcn_mfma_f32_16x16x32_bf16(a[1], b, acc[1][nt], 0, 0, 0);
    }
  }

#pragma unroll
  for (int mt = 0; mt < 2; ++mt)
#pragma unroll
    for (int nt = 0; nt < NT; ++nt)
#pragma unroll
      for (int reg = 0; reg < 4; ++reg) {
        int row = mbase + mt * 16 + quad * 4 + reg;
        if (row < M) Cout[(size_t)row * N + nt * 16 + lc] = f2bf(acc[mt][nt][reg]);
      }
}

// ------------------ aggregation (latency-optimized gather) -----------------
// One node per G = F/2 lanes; 16-deep edge batching. CSR/offs loads are
// non-temporal so the stream doesn't evict the xw gather set from L2.
template <int F>
__global__ __launch_bounds__(256) void agg_fast_kernel(
    const unsigned short* __restrict__ xw, const int* __restrict__ offs,
    const unsigned int* __restrict__ csr, const float* __restrict__ dinv,
    const float* __restrict__ bias, const float* __restrict__ gamma,
    const float* __restrict__ beta, const float* __restrict__ mean,
    const float* __restrict__ var, unsigned short* __restrict__ out, int N) {
  constexpr int G = F / 2;
  constexpr int NPB = 256 / G;
  const int li = threadIdx.x % G;
  const int i = blockIdx.x * NPB + threadIdx.x / G;
  if (i >= N) return;
  const unsigned int* xw32 = (const unsigned int*)xw;
  const float di = dinv[i];
  const int s = __builtin_nontemporal_load(&offs[i]);
  const int e = __builtin_nontemporal_load(&offs[i + 1]);
  float accL = 0.f, accH = 0.f;
  int t = s;
  for (; t + 16 <= e; t += 16) {
    unsigned int ent[16];
#pragma unroll
    for (int j = 0; j < 16; ++j) ent[j] = __builtin_nontemporal_load(&csr[t + j]);
    unsigned int gv[16];
#pragma unroll
    for (int j = 0; j < 16; ++j) gv[j] = xw32[(size_t)(ent[j] & 0xFFFFu) * G + li];
#pragma unroll
    for (int j = 0; j < 16; ++j) {
      float w = __uint_as_float(ent[j] & 0xFFFF0000u);
      accL += w * __uint_as_float(gv[j] << 16);
      accH += w * __uint_as_float(gv[j] & 0xFFFF0000u);
    }
  }
  for (; t + 4 <= e; t += 4) {
    unsigned int ent[4];
#pragma unroll
    for (int j = 0; j < 4; ++j) ent[j] = __builtin_nontemporal_load(&csr[t + j]);
    unsigned int gv[4];
#pragma unroll
    for (int j = 0; j < 4; ++j) gv[j] = xw32[(size_t)(ent[j] & 0xFFFFu) * G + li];
#pragma unroll
    for (int j = 0; j < 4; ++j) {
      float w = __uint_as_float(ent[j] & 0xFFFF0000u);
      accL += w * __uint_as_float(gv[j] << 16);
      accH += w * __uint_as_float(gv[j] & 0xFFFF0000u);
    }
  }
  for (; t < e; ++t) {
    unsigned int ee = __builtin_nontemporal_load(&csr[t]);
    unsigned int gv = xw32[(size_t)(ee & 0xFFFFu) * G + li];
    float w = __uint_as_float(ee & 0xFFFF0000u);
    accL += w * __uint_as_float(gv << 16);
    accH += w * __uint_as_float(gv & 0xFFFF0000u);
  }
  const int f0 = 2 * li, f1 = f0 + 1;
  unsigned int sv = xw32[(size_t)i * G + li];
  float v0 = di * accL + di * di * __uint_as_float(sv << 16) + bias[f0];
  float v1 = di * accH + di * di * __uint_as_float(sv & 0xFFFF0000u) + bias[f1];
  v0 = (v0 - mean[f0]) * rsqrtf(var[f0] + 1e-5f) * gamma[f0] + beta[f0];
  v1 = (v1 - mean[f1]) * rsqrtf(var[f1] + 1e-5f) * gamma[f1] + beta[f1];
  unsigned int packed =
      (unsigned int)f2bf(fmaxf(v0, 0.f)) | ((unsigned int)f2bf(fmaxf(v1, 0.f)) << 16);
  ((unsigned int*)out)[(size_t)i * G + li] = packed;
}

// ------------------------------- edge head ---------------------------------
// B-frags in LDS (shared per block; frees ~64 VGPR), 2 chunks per iteration
// sharing each b-frag -> 8 independent z-row gathers in flight per wave.
__global__ __launch_bounds__(256) void head_mfma_kernel(
    const unsigned short* __restrict__ z, const int* __restrict__ src,
    const int* __restrict__ dst, const unsigned short* __restrict__ bfragH,
    const float* __restrict__ hb1, const float* __restrict__ hw2,
    const float* __restrict__ hb2, float* __restrict__ out, int P) {
  __shared__ short8x sbf[16 * 64];  // [(nt*4+ks)*64 + lane], 16 KB
  const int tid = threadIdx.x;
  {
    const short8x* g = (const short8x*)bfragH;
    for (int t = tid; t < 16 * 64; t += 256) sbf[t] = g[t];
  }
  __syncthreads();
  const int lane = tid & 63;
  const int quad = lane >> 4;
  const int lc = lane & 15;

  float b1v[4], w2v[4];
#pragma unroll
  for (int nt = 0; nt < 4; ++nt) {
    b1v[nt] = hb1[nt * 16 + lc];
    w2v[nt] = hw2[nt * 16 + lc];
  }
  const float bias2 = hb2[0];

  const int nchunks = (P + 15) / 16;
  const int gw = blockIdx.x * 4 + (tid >> 6);
  const int nw = gridDim.x * 4;

  auto load_a = [&](int ch, short8x* a) {
    int p = ch * 16 + lc;
    int pc = p < P ? p : P - 1;
    int s = src[pc], d = dst[pc];
    const unsigned short* zs = z + (size_t)s * 64;
    const unsigned short* zd = z + (size_t)d * 64;
    a[0] = *(const short8x*)(zs + quad * 8);
    a[1] = *(const short8x*)(zs + 32 + quad * 8);
    a[2] = *(const short8x*)(zd + quad * 8);
    a[3] = *(const short8x*)(zd + 32 + quad * 8);
  };
  auto epilogue = [&](int ch, f32x4* acc) {
    float part[4];
#pragma unroll
    for (int reg = 0; reg < 4; ++reg) {
      float sum = 0.f;
#pragma unroll
      for (int nt = 0; nt < 4; ++nt) sum += fmaxf(acc[nt][reg] + b1v[nt], 0.f) * w2v[nt];
      part[reg] = sum;
    }
#pragma unroll
    for (int m = 1; m < 16; m <<= 1) {
#pragma unroll
      for (int reg = 0; reg < 4; ++reg) part[reg] += __shfl_xor(part[reg], m, 64);
    }
    if (lc == 0) {
      int pbase = ch * 16 + quad * 4;
      float4 o;
      o.x = 1.0f / (1.0f + __expf(-(part[0] + bias2)));
      o.y = 1.0f / (1.0f + __expf(-(part[1] + bias2)));
      o.z = 1.0f / (1.0f + __expf(-(part[2] + bias2)));
      o.w = 1.0f / (1.0f + __expf(-(part[3] + bias2)));
      if (pbase + 3 < P) {
        *(float4*)(out + pbase) = o;
      } else {
        float ov[4] = {o.x, o.y, o.z, o.w};
        for (int reg = 0; reg < 4; ++reg)
          if (pbase + reg < P) out[pbase + reg] = ov[reg];
      }
    }
  };

  int ch = gw;
  for (; ch + nw < nchunks; ch += 2 * nw) {
    const int ch1 = ch + nw;
    short8x a0[4], a1[4];
    load_a(ch, a0);
    load_a(ch1, a1);
    f32x4 acc0[4], acc1[4];
#pragma unroll
    for (int nt = 0; nt < 4; ++nt) {
      acc0[nt] = (f32x4){0.f, 0.f, 0.f, 0.f};
      acc1[nt] = (f32x4){0.f, 0.f, 0.f, 0.f};
    }
#pragma unroll
    for (int nt = 0; nt < 4; ++nt)
#pragma unroll
      for (int ks = 0; ks < 4; ++ks) {
        short8x b = sbf[(nt * 4 + ks) * 64 + lane];
        acc0[nt] = __builtin_amdgcn_mfma_f32_16x16x32_bf16(a0[ks], b, acc0[nt], 0, 0, 0);
        acc1[nt] = __builtin_amdgcn_mfma_f32_16x16x32_bf16(a1[ks], b, acc1[nt], 0, 0, 0);
      }
    epilogue(ch, acc0);
    epilogue(ch1, acc1);
  }
  for (; ch < nchunks; ch += nw) {
    short8x a0[4];
    load_a(ch, a0);
    f32x4 acc0[4];
#pragma unroll
    for (int nt = 0; nt < 4; ++nt) acc0[nt] = (f32x4){0.f, 0.f, 0.f, 0.f};
#pragma unroll
    for (int nt = 0; nt < 4; ++nt)
#pragma unroll
      for (int ks = 0; ks < 4; ++ks) {
        short8x b = sbf[(nt * 4 + ks) * 64 + lane];
        acc0[nt] = __builtin_amdgcn_mfma_f32_16x16x32_bf16(a0[ks], b, acc0[nt], 0, 0, 0);
      }
    epilogue(ch, acc0);
  }
}

// ------------------------------- launcher ----------------------------------

extern "C" void kernel_launch(void* const* d_in, const int* in_sizes, int n_in,
                              void* d_out, int out_size, void* d_ws, size_t ws_size,
                              hipStream_t stream) {
  const float* x = (const float*)d_in[0];
  const int* ei = (const int*)d_in[1];
  const int* src = (const int*)d_in[2];
  const int* dst = (const int*)d_in[3];
  const float* W1 = (const float*)d_in[4];
  const float* b1 = (const float*)d_in[5];
  const float* g1 = (const float*)d_in[6];
  const float* be1 = (const float*)d_in[7];
  const float* mu1 = (const float*)d_in[8];
  const float* va1 = (const float*)d_in[9];
  const float* W2 = (const float*)d_in[10];
  const float* b2 = (const float*)d_in[11];
  const float* g2 = (const float*)d_in[12];
  const float* be2 = (const float*)d_in[13];
  const float* mu2 = (const float*)d_in[14];
  const float* va2 = (const float*)d_in[15];
  const float* hW1 = (const float*)d_in[16];
  const float* hb1 = (const float*)d_in[17];
  const float* hW2 = (const float*)d_in[18];
  const float* hb2 = (const float*)d_in[19];
  float* out = (float*)d_out;

  const int N = in_sizes[0] / 512;
  const int E = in_sizes[1] / 2;
  const int P = in_sizes[2];
  const int* row = ei;
  const int* col = ei + E;
  const int NBK = (N + 255) / 256;    // buckets (256 nodes each), <=256
  const int NAB = (E + 4095) / 4096;  // binA blocks

  char* wp = (char*)d_ws;
  auto alloc = [&](size_t bytes) {
    char* p = wp;
    wp += (bytes + 255) & ~(size_t)255;
    return p;
  };
  unsigned short* xw1 = (unsigned short*)alloc((size_t)N * 128 * 2);
  unsigned short* h = (unsigned short*)alloc((size_t)N * 128 * 2);
  unsigned short* xw2 = (unsigned short*)alloc((size_t)N * 64 * 2);
  unsigned short* z = (unsigned short*)alloc((size_t)N * 64 * 2);
  float* dinv = (float*)alloc((size_t)N * 4);
  int* offs = (int*)alloc((size_t)(N + 1) * 4);
  unsigned int* csr = (unsigned int*)alloc((size_t)E * 4);
  unsigned int* staging = (unsigned int*)alloc((size_t)E * 4);
  int* bucket_count = (int*)alloc((size_t)NBK * 4);
  int* bucket_start = (int*)alloc((size_t)(NBK + 1) * 4);
  int* bcur = (int*)alloc((size_t)NBK * 4);
  unsigned short* bfW1 = (unsigned short*)alloc(512 * 128 * 2);
  unsigned short* bfW2 = (unsigned short*)alloc(128 * 64 * 2);
  unsigned short* bfH = (unsigned short*)alloc(128 * 64 * 2);
  (void)ws_size;
  (void)n_in;
  (void)out_size;

  // --- graph structure ---
  hipLaunchKernelGGL(zero_int_kernel, dim3((NBK + 255) / 256), dim3(256), 0, stream, bucket_count,
                     NBK);
  hipLaunchKernelGGL(binA_hist_kernel, dim3(NAB), dim3(256), 0, stream, col, bucket_count, E, NBK);
  hipLaunchKernelGGL(scan_buckets_kernel, dim3(1), dim3(256), 0, stream, bucket_count,
                     bucket_start, bcur, offs + N, NBK, E);
  hipLaunchKernelGGL(binA_scatter_kernel, dim3(NAB), dim3(256), 0, stream, row, col, bcur, staging,
                     E, NBK);
  hipLaunchKernelGGL(binB1_kernel, dim3(NBK), dim3(256), 0, stream, staging, bucket_start, offs,
                     dinv, N);
  hipLaunchKernelGGL(binB2_kernel, dim3(NBK), dim3(512), 0, stream, staging, offs, bucket_start,
                     dinv, csr, N);

  // --- weight fragment prep (one launch) ---
  hipLaunchKernelGGL(prep_all_kernel, dim3(40), dim3(256), 0, stream, W1, W2, hW1, bfW1, bfW2,
                     bfH);

  // --- layer 1 ---
  hipLaunchKernelGGL((mfma_gemm_kernel<512, 128, false>), dim3((N + 127) / 128), dim3(256), 0,
                     stream, x, bfW1, xw1, N);
  hipLaunchKernelGGL((agg_fast_kernel<128>), dim3((N + 3) / 4), dim3(256), 0, stream, xw1, offs,
                     csr, dinv, b1, g1, be1, mu1, va1, h, N);

  // --- layer 2 ---
  hipLaunchKernelGGL((mfma_gemm_kernel<128, 64, true>), dim3((N + 127) / 128), dim3(256), 0, stream,
                     h, bfW2, xw2, N);
  hipLaunchKernelGGL((agg_fast_kernel<64>), dim3((N + 7) / 8), dim3(256), 0, stream, xw2, offs,
                     csr, dinv, b2, g2, be2, mu2, va2, z, N);

  // --- edge head ---
  hipLaunchKernelGGL(head_mfma_kernel, dim3(2048), dim3(256), 0, stream, z, src, dst, bfH, hb1,
                     hW2, hb2, out, P);
}